// Round 9
// baseline (388.863 us; speedup 1.0000x reference)
//
#include <hip/hip_runtime.h>

#define B_ROWS 32768
#define T_BINS 1024

typedef __attribute__((ext_vector_type(8))) _Float16 half8;
typedef __attribute__((ext_vector_type(4))) float floatx4;

__device__ __forceinline__ unsigned long long pack_max(float v, int col) {
    unsigned x = __float_as_uint(v);
    x = (x & 0x80000000u) ? ~x : (x | 0x80000000u);   // monotone float->uint
    return ((unsigned long long)x << 32) | (unsigned)(~col);  // ties -> smaller col
}

// ---------------- convert fp32 -> f16 (RNE), used for W only ----------------
__global__ __launch_bounds__(256) void tof16_kernel(
    const float* __restrict__ src, _Float16* __restrict__ dst, int n4)
{
    int idx = blockIdx.x * 256 + threadIdx.x;
    if (idx >= n4) return;
    float4 x = ((const float4*)src)[idx];
    union { _Float16 h[4]; ushort4 u; } cv;
    cv.h[0] = (_Float16)x.x;
    cv.h[1] = (_Float16)x.y;
    cv.h[2] = (_Float16)x.z;
    cv.h[3] = (_Float16)x.w;
    ((ushort4*)dst)[idx] = cv.u;
}

// ---------------- MEGA R13: W direct global->reg, vmcnt-free slot barrier ----------------
// Evidence chain: R8/R11 per-slot wall ~5100cyc vs ~600cyc issued; R12 doubled TLP at
// same bytes -> null => not latency-TLP. Remaining suspect: __syncthreads emits
// s_waitcnt vmcnt(0), draining asyncs issued ~600cyc earlier each slot (drain
// serialization). R13 removes ALL vmem from the barrier's jurisdiction:
//  - W fragments load DIRECTLY global->registers (wave-private cols; per-lane addrs,
//    4 lanes share each 64B line -> 16 lines/instr, same as async16h), prefetched
//    one slot ahead (wf/wq). No sW, no global_load_lds, no W bank conflicts.
//  - slot barrier = raw "s_waitcnt lgkmcnt(0); s_barrier" (R5-verified pattern):
//    only orders the cross-wave sA ds_write/ds_read. A-prefetch + W-frag loads stay
//    in flight across barriers with compiler-counted vmcnt waits.
// Geometry unchanged from R12: M=64, BK=64, 64 slots, grid 512, 512 thr (8 waves),
// c=2 blocks/CU. LDS: 2x8KB sA + 4KB cand (no overlay needed).
__global__ __launch_bounds__(512, 4) void mega_kernel(
    const float* __restrict__ A, const _Float16* __restrict__ Wh,
    const float* __restrict__ bias, const float* __restrict__ labels,
    float* __restrict__ out_trunc, float* __restrict__ out_S,
    float* __restrict__ loss_acc)
{
    __shared__ _Float16 sA[2][64 * 64];      // 16 KB
    __shared__ unsigned long long cand[8][64];   // 4 KB
    __shared__ float trunc_s[64];

    const int tid  = threadIdx.x;            // 0..511
    const int lane = tid & 63;
    const int w    = tid >> 6;               // wave 0..7 = 32-col group per stage
    const int by   = blockIdx.x;             // row slab 0..511

    // ---- A staging (R12-verified): thread -> (row=tid>>3, phys slot c8=tid&7),
    //      one half8 ds_write; phys c8 holds source chunk c8^x8(row)
    const int arow = tid >> 3;
    const int c8   = tid & 7;
    const int x8a  = (arow ^ (arow >> 3)) & 7;
    const int asc  = c8 ^ x8a;
    const float* Abase = A + (size_t)(by * 64 + arow) * T_BINS + asc * 8;
    const int sAw  = arow * 64 + c8 * 8;

    // ---- fragment geometry ----
    const int l15 = lane & 15;
    const int hi  = lane >> 4;
    const int xc  = (l15 & 7) ^ (l15 >> 3);

    // W fragment source rows: this wave's two 16-col groups (j=0,1)
    const _Float16* Wrow0 = Wh + (size_t)(w * 32 + l15) * T_BINS + hi * 8;       // j=0
    const _Float16* Wrow1 = Wh + (size_t)(w * 32 + 16 + l15) * T_BINS + hi * 8;  // j=1
    // fragment (g,j) at k0: Wrowj + k0 + g*32   (halfs; (g*4+hi)*8 = hi*8 + g*32)

    float run_best[4][4];
    int   run_col[4][4];
#pragma unroll
    for (int i = 0; i < 4; ++i)
#pragma unroll
        for (int r = 0; r < 4; ++r) { run_best[i][r] = -3.4e38f; run_col[i][r] = 0; }

    // ---- prologue: stage A tile 0; load W frags for slot 0; prefetch A tile 1 ----
    {
        float4 f0 = *(const float4*)(Abase + 0);
        float4 f1 = *(const float4*)(Abase + 4);
        half8 hv;
        hv[0] = (_Float16)f0.x; hv[1] = (_Float16)f0.y; hv[2] = (_Float16)f0.z; hv[3] = (_Float16)f0.w;
        hv[4] = (_Float16)f1.x; hv[5] = (_Float16)f1.y; hv[6] = (_Float16)f1.z; hv[7] = (_Float16)f1.w;
        *(half8*)&sA[0][sAw] = hv;
    }
    half8 wf00 = *(const half8*)(Wrow0 + 0);    // (g0,j0) k0=0
    half8 wf01 = *(const half8*)(Wrow1 + 0);    // (g0,j1)
    half8 wf10 = *(const half8*)(Wrow0 + 32);   // (g1,j0)
    half8 wf11 = *(const half8*)(Wrow1 + 32);   // (g1,j1)
    float4 pa0 = *(const float4*)(Abase + 64);
    float4 pa1 = *(const float4*)(Abase + 68);
    asm volatile("s_waitcnt lgkmcnt(0)" ::: "memory");
    __builtin_amdgcn_s_barrier();

    // ---- main loop: 64 slots (4 bx x 16 k-steps of BK=64), vmcnt-free barriers ----
    int n = 0;
    for (int bx = 0; bx < 4; ++bx) {
        const int colbase = bx * 256 + w * 32 + l15;
        float bj[2];
        bj[0] = bias[colbase];
        bj[1] = bias[colbase + 16];

        floatx4 acc[4][2];
#pragma unroll
        for (int i = 0; i < 4; ++i)
#pragma unroll
            for (int j = 0; j < 2; ++j) acc[i][j] = (floatx4){0.f, 0.f, 0.f, 0.f};

        for (int t = 0; t < 16; ++t, ++n) {
            const int cur = n & 1;
            const int nxt = cur ^ 1;
            const int m   = (n + 1) & 63;    // wrap harmless (reloads slot-0 data)
            const int bxn = m >> 4;
            const int k0n = (m & 15) * 64;

            // 1. W fragments for slot n+1 -> wq (global, L2-resident, in flight
            //    across the barrier; consumed by next slot's MFMAs)
            const size_t wkoff = (size_t)(bxn * 256) * T_BINS + k0n;
            half8 wq00 = *(const half8*)(Wrow0 + wkoff + 0);
            half8 wq01 = *(const half8*)(Wrow1 + wkoff + 0);
            half8 wq10 = *(const half8*)(Wrow0 + wkoff + 32);
            half8 wq11 = *(const half8*)(Wrow1 + wkoff + 32);

            // 2. A f32 prefetch for slot n+2 (in flight across barriers)
            const int kq = ((n + 2) & 15) * 64;
            float4 qa0 = *(const float4*)(Abase + kq + 0);
            float4 qa1 = *(const float4*)(Abase + kq + 4);

            // 3. stage A(n+1) from pa regs into the other buffer
            {
                half8 hv;
                hv[0] = (_Float16)pa0.x; hv[1] = (_Float16)pa0.y;
                hv[2] = (_Float16)pa0.z; hv[3] = (_Float16)pa0.w;
                hv[4] = (_Float16)pa1.x; hv[5] = (_Float16)pa1.y;
                hv[6] = (_Float16)pa1.z; hv[7] = (_Float16)pa1.w;
                *(half8*)&sA[nxt][sAw] = hv;
            }
            pa0 = qa0; pa1 = qa1;

            // 4. A fragments from sA[cur] + MFMA with wf (loaded last slot)
#pragma unroll
            for (int g = 0; g < 2; ++g) {
                half8 ah[4];
#pragma unroll
                for (int i = 0; i < 4; ++i)
                    ah[i] = *(const half8*)&sA[cur][(i * 16 + l15) * 64
                                                    + (((g * 4 + hi) ^ xc ^ (i * 2)) * 8)];
                half8 w0 = g ? wf10 : wf00;
                half8 w1 = g ? wf11 : wf01;
#pragma unroll
                for (int i = 0; i < 4; ++i) {
                    acc[i][0] = __builtin_amdgcn_mfma_f32_16x16x32_f16(ah[i], w0, acc[i][0], 0, 0, 0);
                    acc[i][1] = __builtin_amdgcn_mfma_f32_16x16x32_f16(ah[i], w1, acc[i][1], 0, 0, 0);
                }
            }

            // 5. rotate W prefetch regs
            wf00 = wq00; wf01 = wq01; wf10 = wq10; wf11 = wq11;

            // 6. slot barrier: LDS-only ordering (sA write->read); NO vmcnt drain.
            asm volatile("s_waitcnt lgkmcnt(0)" ::: "memory");
            __builtin_amdgcn_s_barrier();
        }

        // fold this bx's acc into the running argmax (cols strictly increase)
#pragma unroll
        for (int i = 0; i < 4; ++i)
#pragma unroll
            for (int r = 0; r < 4; ++r)
#pragma unroll
                for (int j = 0; j < 2; ++j) {
                    float v = acc[i][j][r] + bj[j];
                    if (v > run_best[i][r]) { run_best[i][r] = v; run_col[i][r] = colbase + j * 16; }
                }
    }

    // ---- epilogue (R12-verified): 16-lane reduce -> cand -> wave0 combine ----
#pragma unroll
    for (int i = 0; i < 4; ++i)
#pragma unroll
        for (int r = 0; r < 4; ++r) {
            float best = run_best[i][r];
            int   bc   = run_col[i][r];
#pragma unroll
            for (int off = 8; off >= 1; off >>= 1) {
                float ov = __shfl_xor(best, off, 64);
                int   oc = __shfl_xor(bc, off, 64);
                if (ov > best || (ov == best && oc < bc)) { best = ov; bc = oc; }
            }
            if (l15 == 0)
                cand[w][i * 16 + hi * 4 + r] = pack_max(best, bc);
        }
    __syncthreads();

    if (tid < 64) {
        unsigned long long m01 = cand[0][tid] > cand[1][tid] ? cand[0][tid] : cand[1][tid];
        unsigned long long m23 = cand[2][tid] > cand[3][tid] ? cand[2][tid] : cand[3][tid];
        unsigned long long m45 = cand[4][tid] > cand[5][tid] ? cand[4][tid] : cand[5][tid];
        unsigned long long m67 = cand[6][tid] > cand[7][tid] ? cand[6][tid] : cand[7][tid];
        unsigned long long ma  = m01 > m23 ? m01 : m23;
        unsigned long long mb  = m45 > m67 ? m45 : m67;
        unsigned long long mm  = ma > mb ? ma : mb;
        unsigned col = ~(unsigned)mm;
        float p = (float)col;
        int rowG = by * 64 + tid;
        out_trunc[rowG] = p;
        trunc_s[tid] = p;
        float d = p - labels[rowG];
        float term = d * d * (1.0f / (float)B_ROWS);
#pragma unroll
        for (int off = 32; off >= 1; off >>= 1)
            term += __shfl_down(term, off, 64);
        if (tid == 0) atomicAdd(loss_acc, term);
    }
    __syncthreads();

    // scan phase (R12-verified): wave w handles rows w*8 .. w*8+7
    for (int rr = 0; rr < 8; ++rr) {
        int row  = w * 8 + rr;
        int rowG = by * 64 + row;
        const float* Hrow = A + (size_t)rowG * T_BINS + lane * 16;
        float4 h0 = *(const float4*)(Hrow + 0);
        float4 h1 = *(const float4*)(Hrow + 4);
        float4 h2 = *(const float4*)(Hrow + 8);
        float4 h3 = *(const float4*)(Hrow + 12);
        float hv[16] = {h0.x, h0.y, h0.z, h0.w, h1.x, h1.y, h1.z, h1.w,
                        h2.x, h2.y, h2.z, h2.w, h3.x, h3.y, h3.z, h3.w};
        float vprod[16];
        float run = 1.f;
#pragma unroll
        for (int j = 0; j < 16; ++j) { run *= (1.f - hv[j]); vprod[j] = run; }
        float x = run;
#pragma unroll
        for (int off = 1; off < 64; off <<= 1) {
            float o = __shfl_up(x, off, 64);
            if (lane >= off) x *= o;
        }
        float pre = __shfl_up(x, 1, 64);
        if (lane == 0) pre = 1.f;

        int p  = (int)trunc_s[row];
        int t0 = lane * 16;
        float sv[16];
#pragma unroll
        for (int j = 0; j < 16; ++j) {
            float s = pre * vprod[j];
            int t = t0 + j;
            if (t >= p) s *= __expf((float)(p - t));
            sv[j] = s;
        }
        float* Srow = out_S + (size_t)rowG * T_BINS + lane * 16;
        *(float4*)(Srow + 0)  = (float4){sv[0],  sv[1],  sv[2],  sv[3]};
        *(float4*)(Srow + 4)  = (float4){sv[4],  sv[5],  sv[6],  sv[7]};
        *(float4*)(Srow + 8)  = (float4){sv[8],  sv[9],  sv[10], sv[11]};
        *(float4*)(Srow + 12) = (float4){sv[12], sv[13], sv[14], sv[15]};
    }
}

// ---------------- fp32 fallback path (round-1 kernels), used if ws too small ----------------
#define BMf 64
#define BKf 16
#define LDSS (BMf + 4)
__global__ __launch_bounds__(256) void gemm_argmax_fp32(
    const float* __restrict__ A, const float* __restrict__ W,
    const float* __restrict__ bias, unsigned long long* __restrict__ rec)
{
    __shared__ float As[BKf][LDSS];
    __shared__ float Ws[BKf][LDSS];
    const int tid = threadIdx.x;
    const int tx = tid & 15, ty = tid >> 4;
    const int bx = blockIdx.x, by = blockIdx.y;
    const int ar = tid >> 2, ak = (tid & 3) << 2;
    const float* Arow = A + (size_t)(by * BMf + ar) * T_BINS + ak;
    const float* Wrow = W + (size_t)(bx * BMf + ar) * T_BINS + ak;
    float acc[4][4];
#pragma unroll
    for (int i = 0; i < 4; ++i)
#pragma unroll
        for (int j = 0; j < 4; ++j) acc[i][j] = 0.f;
    for (int k0 = 0; k0 < T_BINS; k0 += BKf) {
        float4 av = *(const float4*)(Arow + k0);
        float4 wvv = *(const float4*)(Wrow + k0);
        As[ak + 0][ar] = av.x; As[ak + 1][ar] = av.y; As[ak + 2][ar] = av.z; As[ak + 3][ar] = av.w;
        Ws[ak + 0][ar] = wvv.x; Ws[ak + 1][ar] = wvv.y; Ws[ak + 2][ar] = wvv.z; Ws[ak + 3][ar] = wvv.w;
        __syncthreads();
#pragma unroll
        for (int k = 0; k < BKf; ++k) {
            float4 a4 = *(const float4*)&As[k][ty * 4];
            float4 w4 = *(const float4*)&Ws[k][tx * 4];
            float aa[4] = {a4.x, a4.y, a4.z, a4.w};
            float ww[4] = {w4.x, w4.y, w4.z, w4.w};
#pragma unroll
            for (int i = 0; i < 4; ++i)
#pragma unroll
                for (int j = 0; j < 4; ++j) acc[i][j] = fmaf(aa[i], ww[j], acc[i][j]);
        }
        __syncthreads();
    }
    const int colBase = bx * BMf + tx * 4;
    float bv[4];
#pragma unroll
    for (int j = 0; j < 4; ++j) bv[j] = bias[colBase + j];
#pragma unroll
    for (int i = 0; i < 4; ++i) {
        float best = acc[i][0] + bv[0];
        int bc = colBase;
#pragma unroll
        for (int j = 1; j < 4; ++j) {
            float v = acc[i][j] + bv[j];
            if (v > best) { best = v; bc = colBase + j; }
        }
#pragma unroll
        for (int off = 8; off >= 1; off >>= 1) {
            float ov = __shfl_xor(best, off, 64);
            int oc = __shfl_xor(bc, off, 64);
            if (ov > best || (ov == best && oc < bc)) { best = ov; bc = oc; }
        }
        if (tx == 0) atomicMax(&rec[by * BMf + ty * 4 + i], pack_max(best, bc));
    }
}

__global__ __launch_bounds__(256) void finalize_kernel(
    const unsigned long long* __restrict__ rec, const float* __restrict__ labels,
    float* __restrict__ out_trunc, float* __restrict__ loss_acc)
{
    int i = blockIdx.x * 256 + threadIdx.x;
    unsigned col = ~(unsigned)(rec[i] & 0xFFFFFFFFull);
    float p = (float)col;
    out_trunc[i] = p;
    float d = p - labels[i];
    float term = d * d * (1.0f / (float)B_ROWS);
#pragma unroll
    for (int off = 32; off >= 1; off >>= 1)
        term += __shfl_down(term, off, 64);
    __shared__ float partials[4];
    int lane = threadIdx.x & 63, wv = threadIdx.x >> 6;
    if (lane == 0) partials[wv] = term;
    __syncthreads();
    if (threadIdx.x == 0)
        atomicAdd(loss_acc, partials[0] + partials[1] + partials[2] + partials[3]);
}

__global__ __launch_bounds__(256) void scan_kernel_f32(
    const float* __restrict__ H, const float* __restrict__ trunc_f,
    float* __restrict__ Sout)
{
    const int row = blockIdx.x;
    const int tid = threadIdx.x;
    const int lane = tid & 63;
    const int wv = tid >> 6;
    const float4 h = *(const float4*)(H + (size_t)row * T_BINS + tid * 4);
    float l0 = 1.f - h.x;
    float l1 = l0 * (1.f - h.y);
    float l2 = l1 * (1.f - h.z);
    float l3 = l2 * (1.f - h.w);
    float x = l3;
#pragma unroll
    for (int off = 1; off < 64; off <<= 1) {
        float o = __shfl_up(x, off, 64);
        if (lane >= off) x *= o;
    }
    float ex = __shfl_up(x, 1, 64);
    if (lane == 0) ex = 1.f;
    __shared__ float wtot[4];
    if (lane == 63) wtot[wv] = x;
    __syncthreads();
    float wpre = 1.f;
#pragma unroll
    for (int w = 0; w < 3; ++w)
        if (w < wv) wpre *= wtot[w];
    float pre = wpre * ex;
    int p = (int)trunc_f[row];
    int t0 = tid * 4;
    float sv[4] = {pre * l0, pre * l1, pre * l2, pre * l3};
#pragma unroll
    for (int j = 0; j < 4; ++j) {
        int t = t0 + j;
        if (t >= p) sv[j] *= __expf((float)(p - t));
    }
    float4 s4 = {sv[0], sv[1], sv[2], sv[3]};
    *(float4*)(Sout + (size_t)row * T_BINS + tid * 4) = s4;
}

extern "C" void kernel_launch(void* const* d_in, const int* in_sizes, int n_in,
                              void* d_out, int out_size, void* d_ws, size_t ws_size,
                              hipStream_t stream)
{
    const float* hazard = (const float*)d_in[0];   // [B, T]
    const float* labels = (const float*)d_in[1];   // [B]
    const float* W      = (const float*)d_in[2];   // [T, T]
    const float* bias   = (const float*)d_in[3];   // [T]

    float* out       = (float*)d_out;
    float* out_trunc = out;                                       // B floats
    float* out_S     = out + B_ROWS;                              // B*T floats
    float* out_loss  = out + B_ROWS + (size_t)B_ROWS * T_BINS;    // 1 float

    hipMemsetAsync(out_loss, 0, sizeof(float), stream);

    const size_t NW = (size_t)T_BINS * T_BINS;
    if (ws_size >= NW * sizeof(_Float16)) {
        // R13: W direct-to-reg mega, vmcnt-free slot barriers
        _Float16* Wh = (_Float16*)d_ws;
        tof16_kernel<<<(int)(NW / 4 / 256), 256, 0, stream>>>(W, Wh, (int)(NW / 4));
        mega_kernel<<<B_ROWS / 64, 512, 0, stream>>>(
            hazard, Wh, bias, labels, out_trunc, out_S, out_loss);
    } else {
        unsigned long long* rec = (unsigned long long*)out_S;
        hipMemsetAsync(rec, 0, (size_t)B_ROWS * sizeof(unsigned long long), stream);
        dim3 ggrid(T_BINS / BMf, B_ROWS / BMf);
        gemm_argmax_fp32<<<ggrid, 256, 0, stream>>>(hazard, W, bias, rec);
        finalize_kernel<<<B_ROWS / 256, 256, 0, stream>>>(rec, labels, out_trunc, out_loss);
        scan_kernel_f32<<<B_ROWS, 256, 0, stream>>>(hazard, out_trunc, out_S);
    }
}

// Round 10
// 348.246 us; speedup vs baseline: 1.1166x; 1.1166x over previous
//
#include <hip/hip_runtime.h>

#define B_ROWS 32768
#define T_BINS 1024

typedef __attribute__((ext_vector_type(8))) _Float16 half8;
typedef __attribute__((ext_vector_type(4))) float floatx4;

__device__ __forceinline__ unsigned long long pack_max(float v, int col) {
    unsigned x = __float_as_uint(v);
    x = (x & 0x80000000u) ? ~x : (x | 0x80000000u);   // monotone float->uint
    return ((unsigned long long)x << 32) | (unsigned)(~col);  // ties -> smaller col
}

__device__ __forceinline__ void async16h(const _Float16* g, _Float16* l) {
    __builtin_amdgcn_global_load_lds(
        (const __attribute__((address_space(1))) unsigned int*)g,
        (__attribute__((address_space(3))) unsigned int*)l,
        16, 0, 0);
}

// ---------------- convert fp32 -> f16 (RNE), used for W only ----------------
__global__ __launch_bounds__(256) void tof16_kernel(
    const float* __restrict__ src, _Float16* __restrict__ dst, int n4)
{
    int idx = blockIdx.x * 256 + threadIdx.x;
    if (idx >= n4) return;
    float4 x = ((const float4*)src)[idx];
    union { _Float16 h[4]; ushort4 u; } cv;
    cv.h[0] = (_Float16)x.x;
    cv.h[1] = (_Float16)x.y;
    cv.h[2] = (_Float16)x.z;
    cv.h[3] = (_Float16)x.w;
    ((ushort4*)dst)[idx] = cv.u;
}

// ---------------- MEGA (R12, session best: 188us kernel / 345.8us total) ----------------
// R14 = R12 restored verbatim after R13 (W direct-to-reg) regressed to 227us.
// Falsification ledger (10 rounds): counted-vmcnt placement null (R5); more blocks/CU
// hurt (R7); c=1 big tile hurt (R9); equal-bytes reshape hurt (R10); more waves/SIMD
// null (R12 vs R11, but R12 kept: -2% and better occupancy headroom); drain-free
// reg-W hurt (R13); nontemporal hurt (R6); setprio null. Only win: fatter slots (R8).
// Structure: M=64 rows/block, BK=64, 64 slots, grid 512 (c=2 blocks/CU), 512 thr
// (8 waves = 8x32-col groups), dbuf sA+sW, one __syncthreads per slot, XOR-swizzled
// LDS (x8(r)=(r^(r>>3))&7 on 16B slots; W swizzle folded into global src k-offset).
__global__ __launch_bounds__(512, 4) void mega_kernel(
    const float* __restrict__ A, const _Float16* __restrict__ Wh,
    const float* __restrict__ bias, const float* __restrict__ labels,
    float* __restrict__ out_trunc, float* __restrict__ out_S,
    float* __restrict__ loss_acc)
{
    __shared__ _Float16 sA[2][64 * 64];      // 16 KB
    __shared__ _Float16 sW[2][256 * 64];     // 64 KB

    const int tid  = threadIdx.x;            // 0..511
    const int lane = tid & 63;
    const int w    = tid >> 6;               // wave 0..7 = 32-col group per stage
    const int by   = blockIdx.x;             // row slab 0..511

    // ---- A staging: thread -> (row=tid>>3, phys slot c8=tid&7), ONE half8 write;
    //      phys slot c8 holds source chunk c8^x8(row), x8(r)=(r^(r>>3))&7
    const int arow = tid >> 3;               // 0..63
    const int c8   = tid & 7;                // 0..7
    const int x8a  = (arow ^ (arow >> 3)) & 7;
    const int asc  = c8 ^ x8a;               // source k-chunk
    const float* Abase = A + (size_t)(by * 64 + arow) * T_BINS + asc * 8;
    const int sAw  = arow * 64 + c8 * 8;     // halfs

    // ---- W staging: 4 asyncs/wave; async r: lane l -> local col w*32+r*8+(l>>3),
    //      phys slot l&7; src chunk = (l&7) ^ l3 ^ ((w&1)*4) ^ r  [x8(col) derived,
    //      bit-disjoint: w*4 mod 8 = (w&1)*4 (bit2), r (bits0-1), no carries]
    const int l3  = lane >> 3;
    const int wsl = lane & 7;
    const int w4  = (w & 1) * 4;

    // ---- fragment reads: phys = (g*4+hi) ^ xc ^ (i*2 | j*2) ^ (w4 for W) ----
    const int l15 = lane & 15;
    const int hi  = lane >> 4;
    const int xc  = (l15 & 7) ^ (l15 >> 3);

    float run_best[4][4];
    int   run_col[4][4];
#pragma unroll
    for (int i = 0; i < 4; ++i)
#pragma unroll
        for (int r = 0; r < 4; ++r) { run_best[i][r] = -3.4e38f; run_col[i][r] = 0; }

    // ---- prologue: stage tile 0 into buf 0; prefetch A regs for tile 1 ----
    {
        float4 f0 = *(const float4*)(Abase + 0);
        float4 f1 = *(const float4*)(Abase + 4);
        half8 hv;
        hv[0] = (_Float16)f0.x; hv[1] = (_Float16)f0.y; hv[2] = (_Float16)f0.z; hv[3] = (_Float16)f0.w;
        hv[4] = (_Float16)f1.x; hv[5] = (_Float16)f1.y; hv[6] = (_Float16)f1.z; hv[7] = (_Float16)f1.w;
        *(half8*)&sA[0][sAw] = hv;
    }
#pragma unroll
    for (int r = 0; r < 4; ++r)
        async16h(Wh + (size_t)(w * 32 + r * 8 + l3) * T_BINS + ((wsl ^ l3 ^ w4 ^ r) * 8),
                 &sW[0][(w * 32 + r * 8) * 64]);
    float4 pa0 = *(const float4*)(Abase + 64);
    float4 pa1 = *(const float4*)(Abase + 68);
    __syncthreads();

    // ---- main loop: 64 tiles (4 bx x 16 k-steps of BK=64), double-buffered ----
    int n = 0;
    for (int bx = 0; bx < 4; ++bx) {
        const int colbase = bx * 256 + w * 32 + l15;
        float bj[2];
        bj[0] = bias[colbase];
        bj[1] = bias[colbase + 16];

        floatx4 acc[4][2];
#pragma unroll
        for (int i = 0; i < 4; ++i)
#pragma unroll
            for (int j = 0; j < 2; ++j) acc[i][j] = (floatx4){0.f, 0.f, 0.f, 0.f};

        for (int t = 0; t < 16; ++t, ++n) {
            const int cur = n & 1;
            const int nxt = cur ^ 1;

            if (n < 63) {   // last slot: nothing left to stage
                const int m   = n + 1;
                const int bxn = m >> 4;
                const int k0n = (m & 15) * 64;

                // 1. W asyncs for tile n+1 (this wave's own 32-col read region)
#pragma unroll
                for (int r = 0; r < 4; ++r)
                    async16h(Wh + (size_t)(bxn * 256 + w * 32 + r * 8 + l3) * T_BINS
                                + k0n + ((wsl ^ l3 ^ w4 ^ r) * 8),
                             &sW[nxt][(w * 32 + r * 8) * 64]);

                // 2. prefetch A regs for tile n+2 (A depends only on k)
                const int kq = ((n + 2) & 15) * 64;
                float4 qa0 = *(const float4*)(Abase + kq + 0);
                float4 qa1 = *(const float4*)(Abase + kq + 4);

                // 3. stage A(n+1) from regs into the other buffer
                {
                    half8 hv;
                    hv[0] = (_Float16)pa0.x; hv[1] = (_Float16)pa0.y;
                    hv[2] = (_Float16)pa0.z; hv[3] = (_Float16)pa0.w;
                    hv[4] = (_Float16)pa1.x; hv[5] = (_Float16)pa1.y;
                    hv[6] = (_Float16)pa1.z; hv[7] = (_Float16)pa1.w;
                    *(half8*)&sA[nxt][sAw] = hv;
                }
                pa0 = qa0; pa1 = qa1;
            }

            // 4. fragments + MFMA: 2 k-subtiles x (4i x 2j) = 16 MFMA/wave/slot
#pragma unroll
            for (int g = 0; g < 2; ++g) {
                half8 ah[4], whf[2];
#pragma unroll
                for (int i = 0; i < 4; ++i)
                    ah[i] = *(const half8*)&sA[cur][(i * 16 + l15) * 64
                                                    + (((g * 4 + hi) ^ xc ^ (i * 2)) * 8)];
#pragma unroll
                for (int j = 0; j < 2; ++j)
                    whf[j] = *(const half8*)&sW[cur][(w * 32 + j * 16 + l15) * 64
                                                     + (((g * 4 + hi) ^ xc ^ (j * 2) ^ w4) * 8)];
#pragma unroll
                for (int i = 0; i < 4; ++i)
#pragma unroll
                    for (int j = 0; j < 2; ++j)
                        acc[i][j] = __builtin_amdgcn_mfma_f32_16x16x32_f16(ah[i], whf[j], acc[i][j], 0, 0, 0);
            }

            // 5. single barrier per slot (drains asyncs + ds_writes, guards swap)
            __syncthreads();
        }

        // fold this bx's acc into the running argmax (cols strictly increase)
#pragma unroll
        for (int i = 0; i < 4; ++i)
#pragma unroll
            for (int r = 0; r < 4; ++r)
#pragma unroll
                for (int j = 0; j < 2; ++j) {
                    float v = acc[i][j][r] + bj[j];
                    if (v > run_best[i][r]) { run_best[i][r] = v; run_col[i][r] = colbase + j * 16; }
                }
    }

    // ---- epilogue: cand (8 waves x 64 rows, 4KB) + trunc_s overlaid on dead sA ----
    unsigned long long (*cand)[64] = reinterpret_cast<unsigned long long (*)[64]>(&sA[0][0]);
    float* trunc_s = reinterpret_cast<float*>(&sA[0][0]) + 1024;   // byte 4096

    // 16-lane (column-lane) reduce; lanes {0,16,32,48} publish per-row candidates
#pragma unroll
    for (int i = 0; i < 4; ++i)
#pragma unroll
        for (int r = 0; r < 4; ++r) {
            float best = run_best[i][r];
            int   bc   = run_col[i][r];
#pragma unroll
            for (int off = 8; off >= 1; off >>= 1) {
                float ov = __shfl_xor(best, off, 64);
                int   oc = __shfl_xor(bc, off, 64);
                if (ov > best || (ov == best && oc < bc)) { best = ov; bc = oc; }
            }
            if (l15 == 0)
                cand[w][i * 16 + hi * 4 + r] = pack_max(best, bc);
        }
    __syncthreads();

    // wave 0: combine 8 col-group candidates per row, write trunc_pos + loss
    if (tid < 64) {
        unsigned long long m01 = cand[0][tid] > cand[1][tid] ? cand[0][tid] : cand[1][tid];
        unsigned long long m23 = cand[2][tid] > cand[3][tid] ? cand[2][tid] : cand[3][tid];
        unsigned long long m45 = cand[4][tid] > cand[5][tid] ? cand[4][tid] : cand[5][tid];
        unsigned long long m67 = cand[6][tid] > cand[7][tid] ? cand[6][tid] : cand[7][tid];
        unsigned long long ma  = m01 > m23 ? m01 : m23;
        unsigned long long mb  = m45 > m67 ? m45 : m67;
        unsigned long long mm  = ma > mb ? ma : mb;
        unsigned col = ~(unsigned)mm;
        float p = (float)col;
        int rowG = by * 64 + tid;
        out_trunc[rowG] = p;
        trunc_s[tid] = p;
        float d = p - labels[rowG];
        float term = d * d * (1.0f / (float)B_ROWS);
#pragma unroll
        for (int off = 32; off >= 1; off >>= 1)
            term += __shfl_down(term, off, 64);
        if (tid == 0) atomicAdd(loss_acc, term);
    }
    __syncthreads();

    // scan phase: wave w handles rows w*8 .. w*8+7; lane covers 16 elements
    for (int rr = 0; rr < 8; ++rr) {
        int row  = w * 8 + rr;
        int rowG = by * 64 + row;
        const float* Hrow = A + (size_t)rowG * T_BINS + lane * 16;
        float4 h0 = *(const float4*)(Hrow + 0);
        float4 h1 = *(const float4*)(Hrow + 4);
        float4 h2 = *(const float4*)(Hrow + 8);
        float4 h3 = *(const float4*)(Hrow + 12);
        float hv[16] = {h0.x, h0.y, h0.z, h0.w, h1.x, h1.y, h1.z, h1.w,
                        h2.x, h2.y, h2.z, h2.w, h3.x, h3.y, h3.z, h3.w};
        float vprod[16];
        float run = 1.f;
#pragma unroll
        for (int j = 0; j < 16; ++j) { run *= (1.f - hv[j]); vprod[j] = run; }
        float x = run;
#pragma unroll
        for (int off = 1; off < 64; off <<= 1) {
            float o = __shfl_up(x, off, 64);
            if (lane >= off) x *= o;
        }
        float pre = __shfl_up(x, 1, 64);
        if (lane == 0) pre = 1.f;

        int p  = (int)trunc_s[row];
        int t0 = lane * 16;
        float sv[16];
#pragma unroll
        for (int j = 0; j < 16; ++j) {
            float s = pre * vprod[j];
            int t = t0 + j;
            if (t >= p) s *= __expf((float)(p - t));
            sv[j] = s;
        }
        float* Srow = out_S + (size_t)rowG * T_BINS + lane * 16;
        *(float4*)(Srow + 0)  = (float4){sv[0],  sv[1],  sv[2],  sv[3]};
        *(float4*)(Srow + 4)  = (float4){sv[4],  sv[5],  sv[6],  sv[7]};
        *(float4*)(Srow + 8)  = (float4){sv[8],  sv[9],  sv[10], sv[11]};
        *(float4*)(Srow + 12) = (float4){sv[12], sv[13], sv[14], sv[15]};
    }
}

// ---------------- fp32 fallback path (round-1 kernels), used if ws too small ----------------
#define BMf 64
#define BKf 16
#define LDSS (BMf + 4)
__global__ __launch_bounds__(256) void gemm_argmax_fp32(
    const float* __restrict__ A, const float* __restrict__ W,
    const float* __restrict__ bias, unsigned long long* __restrict__ rec)
{
    __shared__ float As[BKf][LDSS];
    __shared__ float Ws[BKf][LDSS];
    const int tid = threadIdx.x;
    const int tx = tid & 15, ty = tid >> 4;
    const int bx = blockIdx.x, by = blockIdx.y;
    const int ar = tid >> 2, ak = (tid & 3) << 2;
    const float* Arow = A + (size_t)(by * BMf + ar) * T_BINS + ak;
    const float* Wrow = W + (size_t)(bx * BMf + ar) * T_BINS + ak;
    float acc[4][4];
#pragma unroll
    for (int i = 0; i < 4; ++i)
#pragma unroll
        for (int j = 0; j < 4; ++j) acc[i][j] = 0.f;
    for (int k0 = 0; k0 < T_BINS; k0 += BKf) {
        float4 av = *(const float4*)(Arow + k0);
        float4 wvv = *(const float4*)(Wrow + k0);
        As[ak + 0][ar] = av.x; As[ak + 1][ar] = av.y; As[ak + 2][ar] = av.z; As[ak + 3][ar] = av.w;
        Ws[ak + 0][ar] = wvv.x; Ws[ak + 1][ar] = wvv.y; Ws[ak + 2][ar] = wvv.z; Ws[ak + 3][ar] = wvv.w;
        __syncthreads();
#pragma unroll
        for (int k = 0; k < BKf; ++k) {
            float4 a4 = *(const float4*)&As[k][ty * 4];
            float4 w4 = *(const float4*)&Ws[k][tx * 4];
            float aa[4] = {a4.x, a4.y, a4.z, a4.w};
            float ww[4] = {w4.x, w4.y, w4.z, w4.w};
#pragma unroll
            for (int i = 0; i < 4; ++i)
#pragma unroll
                for (int j = 0; j < 4; ++j) acc[i][j] = fmaf(aa[i], ww[j], acc[i][j]);
        }
        __syncthreads();
    }
    const int colBase = bx * BMf + tx * 4;
    float bv[4];
#pragma unroll
    for (int j = 0; j < 4; ++j) bv[j] = bias[colBase + j];
#pragma unroll
    for (int i = 0; i < 4; ++i) {
        float best = acc[i][0] + bv[0];
        int bc = colBase;
#pragma unroll
        for (int j = 1; j < 4; ++j) {
            float v = acc[i][j] + bv[j];
            if (v > best) { best = v; bc = colBase + j; }
        }
#pragma unroll
        for (int off = 8; off >= 1; off >>= 1) {
            float ov = __shfl_xor(best, off, 64);
            int oc = __shfl_xor(bc, off, 64);
            if (ov > best || (ov == best && oc < bc)) { best = ov; bc = oc; }
        }
        if (tx == 0) atomicMax(&rec[by * BMf + ty * 4 + i], pack_max(best, bc));
    }
}

__global__ __launch_bounds__(256) void finalize_kernel(
    const unsigned long long* __restrict__ rec, const float* __restrict__ labels,
    float* __restrict__ out_trunc, float* __restrict__ loss_acc)
{
    int i = blockIdx.x * 256 + threadIdx.x;
    unsigned col = ~(unsigned)(rec[i] & 0xFFFFFFFFull);
    float p = (float)col;
    out_trunc[i] = p;
    float d = p - labels[i];
    float term = d * d * (1.0f / (float)B_ROWS);
#pragma unroll
    for (int off = 32; off >= 1; off >>= 1)
        term += __shfl_down(term, off, 64);
    __shared__ float partials[4];
    int lane = threadIdx.x & 63, wv = threadIdx.x >> 6;
    if (lane == 0) partials[wv] = term;
    __syncthreads();
    if (threadIdx.x == 0)
        atomicAdd(loss_acc, partials[0] + partials[1] + partials[2] + partials[3]);
}

__global__ __launch_bounds__(256) void scan_kernel_f32(
    const float* __restrict__ H, const float* __restrict__ trunc_f,
    float* __restrict__ Sout)
{
    const int row = blockIdx.x;
    const int tid = threadIdx.x;
    const int lane = tid & 63;
    const int wv = tid >> 6;
    const float4 h = *(const float4*)(H + (size_t)row * T_BINS + tid * 4);
    float l0 = 1.f - h.x;
    float l1 = l0 * (1.f - h.y);
    float l2 = l1 * (1.f - h.z);
    float l3 = l2 * (1.f - h.w);
    float x = l3;
#pragma unroll
    for (int off = 1; off < 64; off <<= 1) {
        float o = __shfl_up(x, off, 64);
        if (lane >= off) x *= o;
    }
    float ex = __shfl_up(x, 1, 64);
    if (lane == 0) ex = 1.f;
    __shared__ float wtot[4];
    if (lane == 63) wtot[wv] = x;
    __syncthreads();
    float wpre = 1.f;
#pragma unroll
    for (int w = 0; w < 3; ++w)
        if (w < wv) wpre *= wtot[w];
    float pre = wpre * ex;
    int p = (int)trunc_f[row];
    int t0 = tid * 4;
    float sv[4] = {pre * l0, pre * l1, pre * l2, pre * l3};
#pragma unroll
    for (int j = 0; j < 4; ++j) {
        int t = t0 + j;
        if (t >= p) sv[j] *= __expf((float)(p - t));
    }
    float4 s4 = {sv[0], sv[1], sv[2], sv[3]};
    *(float4*)(Sout + (size_t)row * T_BINS + tid * 4) = s4;
}

extern "C" void kernel_launch(void* const* d_in, const int* in_sizes, int n_in,
                              void* d_out, int out_size, void* d_ws, size_t ws_size,
                              hipStream_t stream)
{
    const float* hazard = (const float*)d_in[0];   // [B, T]
    const float* labels = (const float*)d_in[1];   // [B]
    const float* W      = (const float*)d_in[2];   // [T, T]
    const float* bias   = (const float*)d_in[3];   // [T]

    float* out       = (float*)d_out;
    float* out_trunc = out;                                       // B floats
    float* out_S     = out + B_ROWS;                              // B*T floats
    float* out_loss  = out + B_ROWS + (size_t)B_ROWS * T_BINS;    // 1 float

    hipMemsetAsync(out_loss, 0, sizeof(float), stream);

    const size_t NW = (size_t)T_BINS * T_BINS;
    if (ws_size >= NW * sizeof(_Float16)) {
        // R12 mega restored (session best: 188us kernel, 345.8us total)
        _Float16* Wh = (_Float16*)d_ws;
        tof16_kernel<<<(int)(NW / 4 / 256), 256, 0, stream>>>(W, Wh, (int)(NW / 4));
        mega_kernel<<<B_ROWS / 64, 512, 0, stream>>>(
            hazard, Wh, bias, labels, out_trunc, out_S, out_loss);
    } else {
        unsigned long long* rec = (unsigned long long*)out_S;
        hipMemsetAsync(rec, 0, (size_t)B_ROWS * sizeof(unsigned long long), stream);
        dim3 ggrid(T_BINS / BMf, B_ROWS / BMf);
        gemm_argmax_fp32<<<ggrid, 256, 0, stream>>>(hazard, W, bias, rec);
        finalize_kernel<<<B_ROWS / 256, 256, 0, stream>>>(rec, labels, out_trunc, out_loss);
        scan_kernel_f32<<<B_ROWS, 256, 0, stream>>>(hazard, out_trunc, out_S);
    }
}